// Round 1
// baseline (211.556 us; speedup 1.0000x reference)
//
#include <hip/hip_runtime.h>

// RotateChordCircularPad: out[b, j, t*16+s] = x[b, row(b,j,t), t*16+s]
//   shift[t] = 0 (t==0) else 2^(t-1)            -> (1u<<t)>>1
//   padded_len = 3 * min(lengths)  (device-computed, 8 values)
//   src = (j + shift) % padded_len
//   row = src % lengths[b]
// B=8, C=240 (T=15 tracks x 16), N = in_sizes[0]/(B*C), max_len = out_size/(B*C).
// Pure gather: memory-bound. One float4 (16B) per thread; coalesced stores,
// 64B-granular gather reads (x fully fits in 256MB LLC so re-reads are cheap).

__global__ __launch_bounds__(256) void rotate_chord_kernel(
    const float* __restrict__ x, const int* __restrict__ lengths,
    float* __restrict__ out, int B, int N, int max_len)
{
    const int b    = blockIdx.y;
    const int idx4 = blockIdx.x * blockDim.x + threadIdx.x; // float4 idx within batch
    const int per_b4 = max_len * 60;                        // 240 floats = 60 float4
    if (idx4 >= per_b4) return;

    // padded_len = 3 * min(lengths): 8 wave-uniform loads, L1/scalar-cached
    int mn = lengths[0];
    for (int i = 1; i < B; ++i) mn = min(mn, lengths[i]);
    const unsigned padded_len = 3u * (unsigned)mn;
    const unsigned len_b      = (unsigned)lengths[b];

    const int c4 = idx4 % 60;            // float4 within the 240-float row (0..59)
    const int j  = idx4 / 60;            // output row
    const int t  = c4 >> 2;              // track 0..14
    const unsigned shift = (1u << t) >> 1;  // 0,1,2,4,...,8192

    unsigned src = (unsigned)j + shift;
    src %= padded_len;
    const unsigned row = src % len_b;

    const float4* __restrict__ xin =
        (const float4*)(x + ((size_t)b * (size_t)N + row) * 240u);
    float4 v = xin[c4];

    float4* __restrict__ o =
        (float4*)(out + ((size_t)b * (size_t)max_len + j) * 240u);
    o[c4] = v;
}

extern "C" void kernel_launch(void* const* d_in, const int* in_sizes, int n_in,
                              void* d_out, int out_size, void* d_ws, size_t ws_size,
                              hipStream_t stream) {
    const float* x       = (const float*)d_in[0];
    const int*   lengths = (const int*)d_in[1];
    float*       out     = (float*)d_out;

    const int B = in_sizes[1];          // 8
    const int C = 240;                  // TRACK_SIZE(16) * T(15)
    const int N = in_sizes[0] / (B * C);        // 16384
    const int max_len = out_size / (B * C);     // max(lengths) == N here

    const int per_b4 = max_len * (C / 4);       // float4s per batch row-block
    dim3 grid((per_b4 + 255) / 256, B);
    rotate_chord_kernel<<<grid, 256, 0, stream>>>(x, lengths, out, B, N, max_len);
}

// Round 2
// 210.070 us; speedup vs baseline: 1.0071x; 1.0071x over previous
//
#include <hip/hip_runtime.h>

// RotateChordCircularPad: out[b, j, t*16+s] = x[b, row(b,j,t), t*16+s]
//   shift[t] = (1u<<t)>>1  (0,1,2,4,...,8192 for T=15 tracks)
//   padded_len = 3 * min(lengths)   (device-computed from the 8 lengths)
//   src = (j + shift) % padded_len; row = src % len_b
// Memory-bound gather. Round-2 changes vs round-1 (211 us):
//   * 4 output rows per thread (j, j+jq, j+2jq, j+3jq) -> 4 independent
//     gather loads in flight per wave (4x MLP; round-1 had exactly 1).
//   * %-divisions replaced by while-subtract: for this problem
//     j+shift < padded_len always (0 iters) and src/len_b < 3 (<=2 iters).
//   * Non-temporal stores: 126 MB write stream bypasses LLC so x (126 MB)
//     stays resident in the 256 MB L3 -> gathered 128B-line second halves
//     hit cache instead of re-fetching HBM.
// Stores remain fully coalesced: per store instruction a wave writes 1 KB
// contiguous (c4 fast-varying across lanes).

typedef float f32x4 __attribute__((ext_vector_type(4)));

__global__ __launch_bounds__(256) void rotate_chord_kernel(
    const float* __restrict__ x, const int* __restrict__ lengths,
    float* __restrict__ out, int B, int N, int max_len, int jq)
{
    const int b    = blockIdx.y;
    const int idx4 = blockIdx.x * blockDim.x + threadIdx.x; // (j0, c4) pair
    if (idx4 >= jq * 60) return;

    // min(lengths): tiny uniform loop, scalar-cached
    int mn = lengths[0];
    for (int i = 1; i < B; ++i) mn = min(mn, lengths[i]);
    const unsigned padded_len = 3u * (unsigned)mn;
    const unsigned len_b      = (unsigned)lengths[b];

    const int c4 = idx4 % 60;               // float4 index within 240-float row
    const int j0 = idx4 / 60;               // base output row
    const int t  = c4 >> 2;                 // track 0..14
    const unsigned shift = (1u << t) >> 1;  // 0,1,2,4,...,8192

    const float* __restrict__ xb = x   + (size_t)b * (size_t)N * 240u;
    float*       __restrict__ ob = out + (size_t)b * (size_t)max_len * 240u;

    unsigned rows[4];
    int      js[4];
    bool     ok[4];
#pragma unroll
    for (int k = 0; k < 4; ++k) {
        const int j = j0 + k * jq;
        js[k] = j;
        ok[k] = (j < max_len);
        unsigned src = (unsigned)j + shift;
        while (src >= padded_len) src -= padded_len;  // 0 iters for this dist
        while (src >= len_b)      src -= len_b;       // <=2 iters
        rows[k] = src;
    }

    f32x4 v[4];
#pragma unroll
    for (int k = 0; k < 4; ++k) {
        if (ok[k])
            v[k] = ((const f32x4*)(xb + (size_t)rows[k] * 240u))[c4];
    }

#pragma unroll
    for (int k = 0; k < 4; ++k) {
        if (ok[k])
            __builtin_nontemporal_store(
                v[k], ((f32x4*)(ob + (size_t)js[k] * 240u)) + c4);
    }
}

extern "C" void kernel_launch(void* const* d_in, const int* in_sizes, int n_in,
                              void* d_out, int out_size, void* d_ws, size_t ws_size,
                              hipStream_t stream) {
    const float* x       = (const float*)d_in[0];
    const int*   lengths = (const int*)d_in[1];
    float*       out     = (float*)d_out;

    const int B = in_sizes[1];                  // 8
    const int C = 240;                          // TRACK_SIZE(16) * T(15)
    const int N = in_sizes[0] / (B * C);        // 16384
    const int max_len = out_size / (B * C);     // 16384 (max length)

    const int jq = (max_len + 3) / 4;           // rows per k-slice
    const int per_b = jq * (C / 4);             // threads per batch
    dim3 grid((per_b + 255) / 256, B);
    rotate_chord_kernel<<<grid, 256, 0, stream>>>(x, lengths, out, B, N, max_len, jq);
}